// Round 14
// baseline (238.990 us; speedup 1.0000x reference)
//
#include <hip/hip_runtime.h>

#define N_NODES 10000
#define E_EDGES 640000
#define IN_CH   512
#define OUT_CH  256
#define HALF_CH 128
#define CSR_CAP (E_EDGES + 16 * N_NODES + 128)  // padded capacity + prefetch slack
#define G_GEMM_X 157                            // ceil(10000/64)
#define G_GEMM  (G_GEMM_X * 2)                  // x2 planes
#define G_SCAT  2500                            // 2500*256 = 640000 edges, 1 edge/thread
#define W_ELEM4 ((OUT_CH * IN_CH) / 4)          // 32768 float4 groups in lin_w

typedef short bf16x8 __attribute__((ext_vector_type(8)));
typedef float f32x4  __attribute__((ext_vector_type(4)));

__device__ __forceinline__ unsigned short f2b(float f) {
    unsigned int u = __float_as_uint(f);
    return (unsigned short)((u + 0x7FFFu + ((u >> 16) & 1u)) >> 16);
}
__device__ __forceinline__ float lo16(unsigned int u) { return __uint_as_float(u << 16); }
__device__ __forceinline__ float hi16(unsigned int u) { return __uint_as_float(u & 0xFFFF0000u); }
__device__ __forceinline__ float b2f(unsigned short u) { return __uint_as_float(((unsigned int)u) << 16); }

// ---------------- degree histogram + w fp32->bf16 conversion (idle-thread fold) ----------------
__global__ void deg_kernel(const int* __restrict__ row, int* __restrict__ deg,
                           const float* __restrict__ w, unsigned short* __restrict__ wb, int E) {
    int t = blockIdx.x * blockDim.x + threadIdx.x;
    if (t < W_ELEM4) {
        float4 v = ((const float4*)w)[t];
        ushort4 o;
        o.x = f2b(v.x); o.y = f2b(v.y); o.z = f2b(v.z); o.w = f2b(v.w);
        ((ushort4*)wb)[t] = o;
    }
    if (t < E) atomicAdd(&deg[row[t]], 1);
}

// ---------------- order-free segment allocation + dinv/sq + pad-slot sentinels ----------------
__global__ void alloc_kernel(const int* __restrict__ deg, int* __restrict__ seg_start,
                             int* __restrict__ cursor32, float* __restrict__ dinv,
                             float* __restrict__ sq, int* __restrict__ counter,
                             int* __restrict__ csr_col, int n) {
    int i = blockIdx.x * blockDim.x + threadIdx.x;
    if (i >= n) return;
    int d = deg[i];
    dinv[i] = (d > 0) ? rsqrtf((float)d) : 0.0f;
    sq[i]   = (d > 0) ? sqrtf((float)d) : 0.0f;
    int pad = (d + 15) & ~15;
    int s = atomicAdd(counter, pad);
    seg_start[i] = s;
    cursor32[i << 5] = s;
    for (int j = d; j < pad; j++) csr_col[s + j] = N_NODES;
}

// ---------------- fused LDS-free GEMM (blocks 0..G_GEMM-1) + edge scatter (rest) -------------
// GEMM: A frags read direct from fp32 x (cvt in-register), B frags direct from bf16 wb
// (0.5 MB, L2-hot). No LDS, no barriers -> scatter blocks run at full occupancy.
// Output: bf16 planar h0b pre-scaled by dinv[m] only (spmm reconstructs fp32 via sq).
__global__ __launch_bounds__(256) void gemm_scatter(const float* __restrict__ x,
                                                    const unsigned short* __restrict__ wb,
                                                    const float* __restrict__ bias,
                                                    const float* __restrict__ dinv,
                                                    unsigned short* __restrict__ h0b,
                                                    const int* __restrict__ row,
                                                    const int* __restrict__ col,
                                                    int* __restrict__ cursor32,
                                                    int* __restrict__ csr_col) {
    int bid = blockIdx.x;
    int tid = threadIdx.x;
    if (bid >= G_GEMM) {
        // ---- scatter path: one edge per thread ----
        int e = (bid - G_GEMM) * 256 + tid;
        if (e < E_EDGES) {
            int r = row[e];
            int c = col[e];
            int p = atomicAdd(&cursor32[r << 5], 1);
            csr_col[p] = c;
        }
        return;
    }
    // ---- gemm path (LDS-free) ----
    int bx = bid % G_GEMM_X;
    int plane = bid / G_GEMM_X;
    int wave = tid >> 6, lane = tid & 63, quad = lane >> 4, l16 = lane & 15;
    int row0 = bx * 64;
    int n0 = plane * 128;
    unsigned short* h0b_p = h0b + (size_t)plane * (N_NODES + 1) * HALF_CH;

    int m = row0 + wave * 16 + l16;
    int mload = (m < N_NODES) ? m : (N_NODES - 1);      // clamp; garbage rows not stored
    const float* xrow = x + (size_t)mload * IN_CH;

    f32x4 acc[8] = {};
    #pragma unroll
    for (int k0 = 0; k0 < IN_CH; k0 += 64) {
        #pragma unroll
        for (int kk = 0; kk < 2; kk++) {
            int k = k0 + kk * 32 + quad * 8;
            float4 a0 = *(const float4*)(xrow + k);
            float4 a1 = *(const float4*)(xrow + k + 4);
            bf16x8 a;
            a[0] = (short)f2b(a0.x); a[1] = (short)f2b(a0.y);
            a[2] = (short)f2b(a0.z); a[3] = (short)f2b(a0.w);
            a[4] = (short)f2b(a1.x); a[5] = (short)f2b(a1.y);
            a[6] = (short)f2b(a1.z); a[7] = (short)f2b(a1.w);
            #pragma unroll
            for (int t = 0; t < 8; t++) {
                bf16x8 b = *(const bf16x8*)(wb + (size_t)(n0 + t * 16 + l16) * IN_CH + k);
                acc[t] = __builtin_amdgcn_mfma_f32_16x16x32_bf16(a, b, acc[t], 0, 0, 0);
            }
        }
    }
    #pragma unroll
    for (int t = 0; t < 8; t++) {
        int lcol = t * 16 + l16;
        int col_ = n0 + lcol;
        float bv = bias[col_];
        #pragma unroll
        for (int r = 0; r < 4; r++) {
            int grow = row0 + wave * 16 + quad * 4 + r;
            if (grow < N_NODES) {
                float v = acc[t][r] + bv;
                h0b_p[(size_t)grow * HALF_CH + lcol] = f2b(v * dinv[grow]);
            }
        }
    }
    // zero the pad row (sentinel gather target) — one block per plane
    if (bx == 0 && tid < 64)
        ((unsigned int*)(h0b_p + (size_t)N_NODES * HALF_CH))[tid] = 0u;
}

// ---------------- SpMM: 4 neighbor rows per VMEM instruction ----------
// 2 waves per node (one per 128-ch plane). sub picks the edge in a quad, l16 picks 16B of
// the row. prev reconstructed from dinv-pre-scaled bf16: prev = b2f(prev_b) * sq[node].
__global__ __launch_bounds__(256) void spmm_kernel(const unsigned short* __restrict__ hb,
                                                   const int* __restrict__ seg_start,
                                                   const int* __restrict__ deg,
                                                   const int* __restrict__ csr_col,
                                                   const float* __restrict__ dinv,
                                                   const float* __restrict__ sq,
                                                   const unsigned short* __restrict__ prev_b,
                                                   const float* __restrict__ wts, int widx,
                                                   unsigned short* __restrict__ yb_out,
                                                   float* __restrict__ axpy_out,
                                                   unsigned short* __restrict__ axpyb_out,
                                                   int n) {
    int W = (blockIdx.x * blockDim.x + threadIdx.x) >> 6;
    int lane = threadIdx.x & 63;
    int plane = (W >= n) ? 1 : 0;
    int node = W - plane * n;
    if (node >= n) return;
    int sub = lane >> 4, l16 = lane & 15;
    size_t pstride = (size_t)(n + 1) * HALF_CH;
    const unsigned short* hp = hb + (size_t)plane * pstride;

    int s = seg_start[node];
    int e = s + ((deg[node] + 15) & ~15);
    float acc[8] = {0.f, 0.f, 0.f, 0.f, 0.f, 0.f, 0.f, 0.f};
    if (s < e) {
        int c0 = csr_col[s + 0  + sub];
        int c1 = csr_col[s + 4  + sub];
        int c2 = csr_col[s + 8  + sub];
        int c3 = csr_col[s + 12 + sub];
        int p = s;
        while (true) {
            int pn = p + 16;
            int n0c = csr_col[pn + 0  + sub];   // prefetch next group's cols (slack-safe)
            int n1c = csr_col[pn + 4  + sub];
            int n2c = csr_col[pn + 8  + sub];
            int n3c = csr_col[pn + 12 + sub];
            uint4 v0 = *(const uint4*)(hp + (size_t)c0 * HALF_CH + l16 * 8);
            uint4 v1 = *(const uint4*)(hp + (size_t)c1 * HALF_CH + l16 * 8);
            uint4 v2 = *(const uint4*)(hp + (size_t)c2 * HALF_CH + l16 * 8);
            uint4 v3 = *(const uint4*)(hp + (size_t)c3 * HALF_CH + l16 * 8);
            acc[0] += lo16(v0.x) + lo16(v1.x) + lo16(v2.x) + lo16(v3.x);
            acc[1] += hi16(v0.x) + hi16(v1.x) + hi16(v2.x) + hi16(v3.x);
            acc[2] += lo16(v0.y) + lo16(v1.y) + lo16(v2.y) + lo16(v3.y);
            acc[3] += hi16(v0.y) + hi16(v1.y) + hi16(v2.y) + hi16(v3.y);
            acc[4] += lo16(v0.z) + lo16(v1.z) + lo16(v2.z) + lo16(v3.z);
            acc[5] += hi16(v0.z) + hi16(v1.z) + hi16(v2.z) + hi16(v3.z);
            acc[6] += lo16(v0.w) + lo16(v1.w) + lo16(v2.w) + lo16(v3.w);
            acc[7] += hi16(v0.w) + hi16(v1.w) + hi16(v2.w) + hi16(v3.w);
            c0 = n0c; c1 = n1c; c2 = n2c; c3 = n3c; p = pn;
            if (p >= e) break;
        }
    }
    #pragma unroll
    for (int k = 0; k < 8; k++) {
        acc[k] += __shfl_xor(acc[k], 16, 64);
        acc[k] += __shfl_xor(acc[k], 32, 64);
    }
    if (sub != 0) return;

    float di = dinv[node];
    float y[8];
    #pragma unroll
    for (int k = 0; k < 8; k++) y[k] = di * acc[k];

    size_t pbase = (size_t)plane * pstride + (size_t)node * HALF_CH + l16 * 8;
    size_t padrow = (size_t)plane * pstride + (size_t)n * HALF_CH + l16 * 8;
    if (yb_out) {
        ushort4 o0, o1;
        o0.x = f2b(di * y[0]); o0.y = f2b(di * y[1]); o0.z = f2b(di * y[2]); o0.w = f2b(di * y[3]);
        o1.x = f2b(di * y[4]); o1.y = f2b(di * y[5]); o1.z = f2b(di * y[6]); o1.w = f2b(di * y[7]);
        *(ushort4*)(yb_out + pbase) = o0;
        *(ushort4*)(yb_out + pbase + 4) = o1;
        if (node == 0) {
            ushort4 z = {0, 0, 0, 0};
            *(ushort4*)(yb_out + padrow) = z;
            *(ushort4*)(yb_out + padrow + 4) = z;
        }
    }
    if (prev_b) {
        float wk = wts[widx];
        float sqn = sq[node];
        ushort4 p0 = *(const ushort4*)(prev_b + pbase);
        ushort4 p1 = *(const ushort4*)(prev_b + pbase + 4);
        float o[8];
        o[0] = b2f(p0.x) * sqn + wk * y[0];
        o[1] = b2f(p0.y) * sqn + wk * y[1];
        o[2] = b2f(p0.z) * sqn + wk * y[2];
        o[3] = b2f(p0.w) * sqn + wk * y[3];
        o[4] = b2f(p1.x) * sqn + wk * y[4];
        o[5] = b2f(p1.y) * sqn + wk * y[5];
        o[6] = b2f(p1.z) * sqn + wk * y[6];
        o[7] = b2f(p1.w) * sqn + wk * y[7];
        if (axpy_out) {
            size_t fbase = (size_t)node * OUT_CH + plane * HALF_CH + l16 * 8;
            float4 f0 = {o[0], o[1], o[2], o[3]};
            float4 f1 = {o[4], o[5], o[6], o[7]};
            *(float4*)(axpy_out + fbase) = f0;
            *(float4*)(axpy_out + fbase + 4) = f1;
        }
        if (axpyb_out) {
            ushort4 b0, b1;
            b0.x = f2b(di * o[0]); b0.y = f2b(di * o[1]); b0.z = f2b(di * o[2]); b0.w = f2b(di * o[3]);
            b1.x = f2b(di * o[4]); b1.y = f2b(di * o[5]); b1.z = f2b(di * o[6]); b1.w = f2b(di * o[7]);
            *(ushort4*)(axpyb_out + pbase) = b0;
            *(ushort4*)(axpyb_out + pbase + 4) = b1;
            if (node == 0) {
                ushort4 z = {0, 0, 0, 0};
                *(ushort4*)(axpyb_out + padrow) = z;
                *(ushort4*)(axpyb_out + padrow + 4) = z;
            }
        }
    }
}

extern "C" void kernel_launch(void* const* d_in, const int* in_sizes, int n_in,
                              void* d_out, int out_size, void* d_ws, size_t ws_size,
                              hipStream_t stream) {
    const float* x     = (const float*)d_in[0];
    const int*   ei    = (const int*)d_in[1];   // [2, E]
    const float* lin_w = (const float*)d_in[2]; // [OUT_CH, IN_CH]
    const float* lin_b = (const float*)d_in[3]; // [OUT_CH]
    const float* wts   = (const float*)d_in[4]; // [K]
    float* out = (float*)d_out;

    char* ws = (char*)d_ws;
    size_t off = 0;
    auto alloc = [&](size_t bytes) -> void* {
        void* p = ws + off;
        off += (bytes + 255) & ~(size_t)255;
        return p;
    };
    int*   meta     = (int*)  alloc((N_NODES + 64) * 4);       // deg + counter (one memset)
    int*   deg      = meta;
    int*   counter  = meta + N_NODES;
    int*   cursor32 = (int*)  alloc((size_t)N_NODES * 32 * 4); // line-padded cursors
    int*   seg_start= (int*)  alloc(N_NODES * 4);
    float* dinv     = (float*)alloc(N_NODES * 4);
    float* sq       = (float*)alloc(N_NODES * 4);
    int*   csr_col  = (int*)  alloc((size_t)CSR_CAP * 4);
    unsigned short* wb    = (unsigned short*)alloc((size_t)OUT_CH * IN_CH * 2);
    unsigned short* h0b   = (unsigned short*)alloc((size_t)2 * (N_NODES + 1) * HALF_CH * 2);
    unsigned short* out1b = (unsigned short*)alloc((size_t)2 * (N_NODES + 1) * HALF_CH * 2);
    unsigned short* t2b   = (unsigned short*)alloc((size_t)2 * (N_NODES + 1) * HALF_CH * 2);

    hipMemsetAsync(meta, 0, (N_NODES + 64) * 4, stream);

    const int* row = ei;
    const int* col = ei + E_EDGES;

    deg_kernel<<<(E_EDGES + 255) / 256, 256, 0, stream>>>(row, deg, lin_w, wb, E_EDGES);
    alloc_kernel<<<(N_NODES + 255) / 256, 256, 0, stream>>>(deg, seg_start, cursor32, dinv,
                                                            sq, counter, csr_col, N_NODES);

    // fused: LDS-free GEMM (h0b bf16 planar pre-scaled) || CSR scatter
    gemm_scatter<<<G_GEMM + G_SCAT, 256, 0, stream>>>(x, wb, lin_b, dinv, h0b,
                                                      row, col, cursor32, csr_col);

    int sgrid = (2 * N_NODES + 3) / 4; // 2 waves/node, 4 waves/block
    // out1b = dinv*(h0 + w0 * spmm(h0)), h0 reconstructed from h0b
    spmm_kernel<<<sgrid, 256, 0, stream>>>(h0b, seg_start, deg, csr_col, dinv, sq, h0b,
                                           wts, 0, nullptr, nullptr, out1b, N_NODES);
    // t2b = dinv*spmm(out1)
    spmm_kernel<<<sgrid, 256, 0, stream>>>(out1b, seg_start, deg, csr_col, dinv, sq, nullptr,
                                           wts, 0, t2b, nullptr, nullptr, N_NODES);
    // out = out1 + w1 * spmm(t2), out1 reconstructed from out1b  (fp32 final)
    spmm_kernel<<<sgrid, 256, 0, stream>>>(t2b, seg_start, deg, csr_col, dinv, sq, out1b,
                                           wts, 1, nullptr, out, nullptr, N_NODES);
}

// Round 16
// 235.902 us; speedup vs baseline: 1.0131x; 1.0131x over previous
//
#include <hip/hip_runtime.h>

#define N_NODES 10000
#define E_EDGES 640000
#define IN_CH   512
#define OUT_CH  256
#define HALF_CH 128
#define CSR_CAP (E_EDGES + 16 * N_NODES + 128)  // padded capacity + prefetch slack
#define G_GEMM_X 157                            // ceil(10000/64)
#define G_GEMM  (G_GEMM_X * 2)                  // x2 planes
#define G_SCAT  2500                            // 2500*256 = 640000 edges, 1 edge/thread

typedef short bf16x8 __attribute__((ext_vector_type(8)));
typedef float f32x4  __attribute__((ext_vector_type(4)));

__device__ __forceinline__ unsigned short f2b(float f) {
    unsigned int u = __float_as_uint(f);
    return (unsigned short)((u + 0x7FFFu + ((u >> 16) & 1u)) >> 16);
}
__device__ __forceinline__ float lo16(unsigned int u) { return __uint_as_float(u << 16); }
__device__ __forceinline__ float hi16(unsigned int u) { return __uint_as_float(u & 0xFFFF0000u); }
__device__ __forceinline__ float b2f(unsigned short u) { return __uint_as_float(((unsigned int)u) << 16); }

// ---------------- degree histogram (pure) ----------------
__global__ void deg_kernel(const int* __restrict__ row, int* __restrict__ deg, int E) {
    int e = blockIdx.x * blockDim.x + threadIdx.x;
    if (e < E) atomicAdd(&deg[row[e]], 1);
}

// ---------------- order-free segment allocation + dinv/sq + pad-slot sentinels ----------------
__global__ void alloc_kernel(const int* __restrict__ deg, int* __restrict__ seg_start,
                             int* __restrict__ cursor32, float* __restrict__ dinv,
                             float* __restrict__ sq, int* __restrict__ counter,
                             int* __restrict__ csr_col, int n) {
    int i = blockIdx.x * blockDim.x + threadIdx.x;
    if (i >= n) return;
    int d = deg[i];
    dinv[i] = (d > 0) ? rsqrtf((float)d) : 0.0f;
    sq[i]   = (d > 0) ? sqrtf((float)d) : 0.0f;
    int pad = (d + 15) & ~15;
    int s = atomicAdd(counter, pad);
    seg_start[i] = s;
    cursor32[i << 5] = s;
    for (int j = d; j < pad; j++) csr_col[s + j] = N_NODES;
}

// ---------------- fused GEMM (blocks 0..G_GEMM-1) + edge scatter (rest) ----------------
// GEMM writes ONLY bf16 planar h0b pre-scaled by dinv[m] (spmm reconstructs fp32 via sq).
__global__ __launch_bounds__(256) void gemm_scatter(const float* __restrict__ x,
                                                    const float* __restrict__ w,
                                                    const float* __restrict__ bias,
                                                    const float* __restrict__ dinv,
                                                    unsigned short* __restrict__ h0b,
                                                    const int* __restrict__ row,
                                                    const int* __restrict__ col,
                                                    int* __restrict__ cursor32,
                                                    int* __restrict__ csr_col) {
    __shared__ unsigned short As[64][72];
    __shared__ unsigned short Bs[128][72];
    int bid = blockIdx.x;
    int tid = threadIdx.x;
    if (bid >= G_GEMM) {
        // ---- scatter path: one edge per thread ----
        int e = (bid - G_GEMM) * 256 + tid;
        if (e < E_EDGES) {
            int r = row[e];
            int c = col[e];
            int p = atomicAdd(&cursor32[r << 5], 1);
            csr_col[p] = c;
        }
        return;
    }
    // ---- gemm path ----
    int bx = bid % G_GEMM_X;
    int plane = bid / G_GEMM_X;
    int wave = tid >> 6, lane = tid & 63, quad = lane >> 4, l16 = lane & 15;
    int row0 = bx * 64;
    int n0 = plane * 128;
    unsigned short* h0b_p = h0b + (size_t)plane * (N_NODES + 1) * HALF_CH;

    int ar = tid >> 2;
    int aseg = (tid & 3) * 16;
    int br = tid >> 1;
    int bseg = (tid & 1) * 32;

    f32x4 acc[8] = {};
    for (int k0 = 0; k0 < IN_CH; k0 += 64) {
        {
            int gr = row0 + ar;
            if (gr < N_NODES) {
                const float4* src = (const float4*)(x + (size_t)gr * IN_CH + k0 + aseg);
                #pragma unroll
                for (int i = 0; i < 4; i++) {
                    float4 v = src[i];
                    ushort4 o;
                    o.x = f2b(v.x); o.y = f2b(v.y); o.z = f2b(v.z); o.w = f2b(v.w);
                    *(ushort4*)&As[ar][aseg + i * 4] = o;
                }
            } else {
                ushort4 z = {0, 0, 0, 0};
                #pragma unroll
                for (int i = 0; i < 4; i++) *(ushort4*)&As[ar][aseg + i * 4] = z;
            }
        }
        {
            const float4* src = (const float4*)(w + (size_t)(n0 + br) * IN_CH + k0 + bseg);
            #pragma unroll
            for (int i = 0; i < 8; i++) {
                float4 v = src[i];
                ushort4 o;
                o.x = f2b(v.x); o.y = f2b(v.y); o.z = f2b(v.z); o.w = f2b(v.w);
                *(ushort4*)&Bs[br][bseg + i * 4] = o;
            }
        }
        __syncthreads();
        #pragma unroll
        for (int kk = 0; kk < 2; kk++) {
            bf16x8 a = *(const bf16x8*)&As[wave * 16 + l16][kk * 32 + quad * 8];
            #pragma unroll
            for (int t = 0; t < 8; t++) {
                bf16x8 b = *(const bf16x8*)&Bs[t * 16 + l16][kk * 32 + quad * 8];
                acc[t] = __builtin_amdgcn_mfma_f32_16x16x32_bf16(a, b, acc[t], 0, 0, 0);
            }
        }
        __syncthreads();
    }
    #pragma unroll
    for (int t = 0; t < 8; t++) {
        int lcol = t * 16 + l16;
        int col_ = n0 + lcol;
        float bv = bias[col_];
        #pragma unroll
        for (int r = 0; r < 4; r++) {
            int grow = row0 + wave * 16 + quad * 4 + r;
            if (grow < N_NODES) {
                float v = acc[t][r] + bv;
                h0b_p[(size_t)grow * HALF_CH + lcol] = f2b(v * dinv[grow]);
            }
        }
    }
    // zero the pad row (sentinel gather target) — one block per plane
    if (bx == 0 && tid < 64)
        ((unsigned int*)(h0b_p + (size_t)N_NODES * HALF_CH))[tid] = 0u;
}

// ---------------- SpMM: XCD-plane-partitioned, 4 neighbor rows per VMEM instruction ------
// plane = blockIdx&1 (all 4 waves of a block on the same plane): under the %8 round-robin
// block->XCD heuristic, each XCD touches only ONE 2.56MB plane -> fits per-XCD L2.
// sub = lane>>4 picks the edge in a quad, l16 picks 16B of the 256B row.
// prev reconstructed from dinv-pre-scaled bf16: prev = b2f(prev_b) * sq[node].
__global__ __launch_bounds__(256) void spmm_kernel(const unsigned short* __restrict__ hb,
                                                   const int* __restrict__ seg_start,
                                                   const int* __restrict__ deg,
                                                   const int* __restrict__ csr_col,
                                                   const float* __restrict__ dinv,
                                                   const float* __restrict__ sq,
                                                   const unsigned short* __restrict__ prev_b,
                                                   const float* __restrict__ wts, int widx,
                                                   unsigned short* __restrict__ yb_out,
                                                   float* __restrict__ axpy_out,
                                                   unsigned short* __restrict__ axpyb_out,
                                                   int n) {
    int plane = blockIdx.x & 1;
    int node = (blockIdx.x >> 1) * 4 + (threadIdx.x >> 6);
    int lane = threadIdx.x & 63;
    if (node >= n) return;
    int sub = lane >> 4, l16 = lane & 15;
    size_t pstride = (size_t)(n + 1) * HALF_CH;
    const unsigned short* hp = hb + (size_t)plane * pstride;

    int s = seg_start[node];
    int e = s + ((deg[node] + 15) & ~15);
    float acc[8] = {0.f, 0.f, 0.f, 0.f, 0.f, 0.f, 0.f, 0.f};
    if (s < e) {
        int c0 = csr_col[s + 0  + sub];
        int c1 = csr_col[s + 4  + sub];
        int c2 = csr_col[s + 8  + sub];
        int c3 = csr_col[s + 12 + sub];
        int p = s;
        while (true) {
            int pn = p + 16;
            int n0c = csr_col[pn + 0  + sub];   // prefetch next group's cols (slack-safe)
            int n1c = csr_col[pn + 4  + sub];
            int n2c = csr_col[pn + 8  + sub];
            int n3c = csr_col[pn + 12 + sub];
            uint4 v0 = *(const uint4*)(hp + (size_t)c0 * HALF_CH + l16 * 8);
            uint4 v1 = *(const uint4*)(hp + (size_t)c1 * HALF_CH + l16 * 8);
            uint4 v2 = *(const uint4*)(hp + (size_t)c2 * HALF_CH + l16 * 8);
            uint4 v3 = *(const uint4*)(hp + (size_t)c3 * HALF_CH + l16 * 8);
            acc[0] += lo16(v0.x) + lo16(v1.x) + lo16(v2.x) + lo16(v3.x);
            acc[1] += hi16(v0.x) + hi16(v1.x) + hi16(v2.x) + hi16(v3.x);
            acc[2] += lo16(v0.y) + lo16(v1.y) + lo16(v2.y) + lo16(v3.y);
            acc[3] += hi16(v0.y) + hi16(v1.y) + hi16(v2.y) + hi16(v3.y);
            acc[4] += lo16(v0.z) + lo16(v1.z) + lo16(v2.z) + lo16(v3.z);
            acc[5] += hi16(v0.z) + hi16(v1.z) + hi16(v2.z) + hi16(v3.z);
            acc[6] += lo16(v0.w) + lo16(v1.w) + lo16(v2.w) + lo16(v3.w);
            acc[7] += hi16(v0.w) + hi16(v1.w) + hi16(v2.w) + hi16(v3.w);
            c0 = n0c; c1 = n1c; c2 = n2c; c3 = n3c; p = pn;
            if (p >= e) break;
        }
    }
    #pragma unroll
    for (int k = 0; k < 8; k++) {
        acc[k] += __shfl_xor(acc[k], 16, 64);
        acc[k] += __shfl_xor(acc[k], 32, 64);
    }
    if (sub != 0) return;

    float di = dinv[node];
    float y[8];
    #pragma unroll
    for (int k = 0; k < 8; k++) y[k] = di * acc[k];

    size_t pbase = (size_t)plane * pstride + (size_t)node * HALF_CH + l16 * 8;
    size_t padrow = (size_t)plane * pstride + (size_t)n * HALF_CH + l16 * 8;
    if (yb_out) {
        ushort4 o0, o1;
        o0.x = f2b(di * y[0]); o0.y = f2b(di * y[1]); o0.z = f2b(di * y[2]); o0.w = f2b(di * y[3]);
        o1.x = f2b(di * y[4]); o1.y = f2b(di * y[5]); o1.z = f2b(di * y[6]); o1.w = f2b(di * y[7]);
        *(ushort4*)(yb_out + pbase) = o0;
        *(ushort4*)(yb_out + pbase + 4) = o1;
        if (node == 0) {
            ushort4 z = {0, 0, 0, 0};
            *(ushort4*)(yb_out + padrow) = z;
            *(ushort4*)(yb_out + padrow + 4) = z;
        }
    }
    if (prev_b) {
        float wk = wts[widx];
        float sqn = sq[node];
        ushort4 p0 = *(const ushort4*)(prev_b + pbase);
        ushort4 p1 = *(const ushort4*)(prev_b + pbase + 4);
        float o[8];
        o[0] = b2f(p0.x) * sqn + wk * y[0];
        o[1] = b2f(p0.y) * sqn + wk * y[1];
        o[2] = b2f(p0.z) * sqn + wk * y[2];
        o[3] = b2f(p0.w) * sqn + wk * y[3];
        o[4] = b2f(p1.x) * sqn + wk * y[4];
        o[5] = b2f(p1.y) * sqn + wk * y[5];
        o[6] = b2f(p1.z) * sqn + wk * y[6];
        o[7] = b2f(p1.w) * sqn + wk * y[7];
        if (axpy_out) {
            size_t fbase = (size_t)node * OUT_CH + plane * HALF_CH + l16 * 8;
            float4 f0 = {o[0], o[1], o[2], o[3]};
            float4 f1 = {o[4], o[5], o[6], o[7]};
            *(float4*)(axpy_out + fbase) = f0;
            *(float4*)(axpy_out + fbase + 4) = f1;
        }
        if (axpyb_out) {
            ushort4 b0, b1;
            b0.x = f2b(di * o[0]); b0.y = f2b(di * o[1]); b0.z = f2b(di * o[2]); b0.w = f2b(di * o[3]);
            b1.x = f2b(di * o[4]); b1.y = f2b(di * o[5]); b1.z = f2b(di * o[6]); b1.w = f2b(di * o[7]);
            *(ushort4*)(axpyb_out + pbase) = b0;
            *(ushort4*)(axpyb_out + pbase + 4) = b1;
            if (node == 0) {
                ushort4 z = {0, 0, 0, 0};
                *(ushort4*)(axpyb_out + padrow) = z;
                *(ushort4*)(axpyb_out + padrow + 4) = z;
            }
        }
    }
}

extern "C" void kernel_launch(void* const* d_in, const int* in_sizes, int n_in,
                              void* d_out, int out_size, void* d_ws, size_t ws_size,
                              hipStream_t stream) {
    const float* x     = (const float*)d_in[0];
    const int*   ei    = (const int*)d_in[1];   // [2, E]
    const float* lin_w = (const float*)d_in[2]; // [OUT_CH, IN_CH]
    const float* lin_b = (const float*)d_in[3]; // [OUT_CH]
    const float* wts   = (const float*)d_in[4]; // [K]
    float* out = (float*)d_out;

    char* ws = (char*)d_ws;
    size_t off = 0;
    auto alloc = [&](size_t bytes) -> void* {
        void* p = ws + off;
        off += (bytes + 255) & ~(size_t)255;
        return p;
    };
    int*   meta     = (int*)  alloc((N_NODES + 64) * 4);       // deg + counter (one memset)
    int*   deg      = meta;
    int*   counter  = meta + N_NODES;
    int*   cursor32 = (int*)  alloc((size_t)N_NODES * 32 * 4); // line-padded cursors
    int*   seg_start= (int*)  alloc(N_NODES * 4);
    float* dinv     = (float*)alloc(N_NODES * 4);
    float* sq       = (float*)alloc(N_NODES * 4);
    int*   csr_col  = (int*)  alloc((size_t)CSR_CAP * 4);
    unsigned short* h0b   = (unsigned short*)alloc((size_t)2 * (N_NODES + 1) * HALF_CH * 2);
    unsigned short* out1b = (unsigned short*)alloc((size_t)2 * (N_NODES + 1) * HALF_CH * 2);
    unsigned short* t2b   = (unsigned short*)alloc((size_t)2 * (N_NODES + 1) * HALF_CH * 2);

    hipMemsetAsync(meta, 0, (N_NODES + 64) * 4, stream);

    const int* row = ei;
    const int* col = ei + E_EDGES;

    deg_kernel<<<(E_EDGES + 255) / 256, 256, 0, stream>>>(row, deg, E_EDGES);
    alloc_kernel<<<(N_NODES + 255) / 256, 256, 0, stream>>>(deg, seg_start, cursor32, dinv,
                                                            sq, counter, csr_col, N_NODES);

    // fused: GEMM (h0b bf16 planar pre-scaled only) || CSR scatter
    gemm_scatter<<<G_GEMM + G_SCAT, 256, 0, stream>>>(x, lin_w, lin_b, dinv, h0b,
                                                      row, col, cursor32, csr_col);

    int sgrid = 2 * ((N_NODES + 3) / 4); // plane = bid&1, 4 nodes/block
    // out1b = dinv*(h0 + w0 * spmm(h0)), h0 reconstructed from h0b
    spmm_kernel<<<sgrid, 256, 0, stream>>>(h0b, seg_start, deg, csr_col, dinv, sq, h0b,
                                           wts, 0, nullptr, nullptr, out1b, N_NODES);
    // t2b = dinv*spmm(out1)
    spmm_kernel<<<sgrid, 256, 0, stream>>>(out1b, seg_start, deg, csr_col, dinv, sq, nullptr,
                                           wts, 0, t2b, nullptr, nullptr, N_NODES);
    // out = out1 + w1 * spmm(t2), out1 reconstructed from out1b  (fp32 final)
    spmm_kernel<<<sgrid, 256, 0, stream>>>(t2b, seg_start, deg, csr_col, dinv, sq, out1b,
                                           wts, 1, nullptr, out, nullptr, N_NODES);
}

// Round 17
// 220.915 us; speedup vs baseline: 1.0818x; 1.0678x over previous
//
#include <hip/hip_runtime.h>

#define N_NODES 10000
#define E_EDGES 640000
#define IN_CH   512
#define OUT_CH  256
#define HALF_CH 128
#define CSR_CAP (E_EDGES + 16 * N_NODES + 128)  // padded capacity + prefetch slack
#define G_GEMM_X 157                            // ceil(10000/64)
#define G_GEMM  (G_GEMM_X * 2)                  // x2 planes
#define G_SCAT  2500                            // 2500*256 = 640000 edges, 1 edge/thread

typedef short bf16x8 __attribute__((ext_vector_type(8)));
typedef float f32x4  __attribute__((ext_vector_type(4)));

__device__ __forceinline__ unsigned short f2b(float f) {
    unsigned int u = __float_as_uint(f);
    return (unsigned short)((u + 0x7FFFu + ((u >> 16) & 1u)) >> 16);
}
__device__ __forceinline__ float lo16(unsigned int u) { return __uint_as_float(u << 16); }
__device__ __forceinline__ float hi16(unsigned int u) { return __uint_as_float(u & 0xFFFF0000u); }
__device__ __forceinline__ float b2f(unsigned short u) { return __uint_as_float(((unsigned int)u) << 16); }

// ---------------- degree histogram into line-padded slots (cursor32[(r<<5)+1]) ----------------
// One node per 128B line: ~64 atomic bumps/line instead of ~2048 (32 nodes/line) — kills
// cross-XCD line ping-pong (same fix that helped the scatter cursor in R12).
__global__ void deg_kernel(const int* __restrict__ row, int* __restrict__ cursor32, int E) {
    int e = blockIdx.x * blockDim.x + threadIdx.x;
    if (e < E) atomicAdd(&cursor32[(row[e] << 5) + 1], 1);
}

// ---------------- order-free segment allocation + dinv/sq + pad-slot sentinels ----------------
// seg[i] = {start, start+padded} (int2, single 8B load in spmm). cursor32[i<<5] = start.
__global__ void alloc_kernel(int* __restrict__ cursor32, int2* __restrict__ seg,
                             float* __restrict__ dinv, float* __restrict__ sq,
                             int* __restrict__ counter, int* __restrict__ csr_col, int n) {
    int i = blockIdx.x * blockDim.x + threadIdx.x;
    if (i >= n) return;
    int d = cursor32[(i << 5) + 1];
    dinv[i] = (d > 0) ? rsqrtf((float)d) : 0.0f;
    sq[i]   = (d > 0) ? sqrtf((float)d) : 0.0f;
    int pad = (d + 15) & ~15;
    int s = atomicAdd(counter, pad);
    seg[i] = make_int2(s, s + pad);
    cursor32[i << 5] = s;
    for (int j = d; j < pad; j++) csr_col[s + j] = N_NODES;
}

// ---------------- fused GEMM (blocks 0..G_GEMM-1) + edge scatter (rest) ----------------
// GEMM writes ONLY bf16 planar h0b pre-scaled by dinv[m] (spmm reconstructs fp32 via sq).
__global__ __launch_bounds__(256) void gemm_scatter(const float* __restrict__ x,
                                                    const float* __restrict__ w,
                                                    const float* __restrict__ bias,
                                                    const float* __restrict__ dinv,
                                                    unsigned short* __restrict__ h0b,
                                                    const int* __restrict__ row,
                                                    const int* __restrict__ col,
                                                    int* __restrict__ cursor32,
                                                    int* __restrict__ csr_col) {
    __shared__ unsigned short As[64][72];
    __shared__ unsigned short Bs[128][72];
    int bid = blockIdx.x;
    int tid = threadIdx.x;
    if (bid >= G_GEMM) {
        // ---- scatter path: one edge per thread ----
        int e = (bid - G_GEMM) * 256 + tid;
        if (e < E_EDGES) {
            int r = row[e];
            int c = col[e];
            int p = atomicAdd(&cursor32[r << 5], 1);
            csr_col[p] = c;
        }
        return;
    }
    // ---- gemm path ----
    int bx = bid % G_GEMM_X;
    int plane = bid / G_GEMM_X;
    int wave = tid >> 6, lane = tid & 63, quad = lane >> 4, l16 = lane & 15;
    int row0 = bx * 64;
    int n0 = plane * 128;
    unsigned short* h0b_p = h0b + (size_t)plane * (N_NODES + 1) * HALF_CH;

    int ar = tid >> 2;
    int aseg = (tid & 3) * 16;
    int br = tid >> 1;
    int bseg = (tid & 1) * 32;

    f32x4 acc[8] = {};
    for (int k0 = 0; k0 < IN_CH; k0 += 64) {
        {
            int gr = row0 + ar;
            if (gr < N_NODES) {
                const float4* src = (const float4*)(x + (size_t)gr * IN_CH + k0 + aseg);
                #pragma unroll
                for (int i = 0; i < 4; i++) {
                    float4 v = src[i];
                    ushort4 o;
                    o.x = f2b(v.x); o.y = f2b(v.y); o.z = f2b(v.z); o.w = f2b(v.w);
                    *(ushort4*)&As[ar][aseg + i * 4] = o;
                }
            } else {
                ushort4 z = {0, 0, 0, 0};
                #pragma unroll
                for (int i = 0; i < 4; i++) *(ushort4*)&As[ar][aseg + i * 4] = z;
            }
        }
        {
            const float4* src = (const float4*)(w + (size_t)(n0 + br) * IN_CH + k0 + bseg);
            #pragma unroll
            for (int i = 0; i < 8; i++) {
                float4 v = src[i];
                ushort4 o;
                o.x = f2b(v.x); o.y = f2b(v.y); o.z = f2b(v.z); o.w = f2b(v.w);
                *(ushort4*)&Bs[br][bseg + i * 4] = o;
            }
        }
        __syncthreads();
        #pragma unroll
        for (int kk = 0; kk < 2; kk++) {
            bf16x8 a = *(const bf16x8*)&As[wave * 16 + l16][kk * 32 + quad * 8];
            #pragma unroll
            for (int t = 0; t < 8; t++) {
                bf16x8 b = *(const bf16x8*)&Bs[t * 16 + l16][kk * 32 + quad * 8];
                acc[t] = __builtin_amdgcn_mfma_f32_16x16x32_bf16(a, b, acc[t], 0, 0, 0);
            }
        }
        __syncthreads();
    }
    #pragma unroll
    for (int t = 0; t < 8; t++) {
        int lcol = t * 16 + l16;
        int col_ = n0 + lcol;
        float bv = bias[col_];
        #pragma unroll
        for (int r = 0; r < 4; r++) {
            int grow = row0 + wave * 16 + quad * 4 + r;
            if (grow < N_NODES) {
                float v = acc[t][r] + bv;
                h0b_p[(size_t)grow * HALF_CH + lcol] = f2b(v * dinv[grow]);
            }
        }
    }
    // zero the pad row (sentinel gather target) — one block per plane
    if (bx == 0 && tid < 64)
        ((unsigned int*)(h0b_p + (size_t)N_NODES * HALF_CH))[tid] = 0u;
}

// ---------------- SpMM: XCD-plane-partitioned, 4 neighbor rows per VMEM instruction ------
// plane = blockIdx&1 (all 4 waves of a block on the same plane). sub = lane>>4 picks the
// edge in a quad, l16 picks 16B of the 256B row. seg int2 = {start, padded end}.
// prev reconstructed from dinv-pre-scaled bf16: prev = b2f(prev_b) * sq[node].
__global__ __launch_bounds__(256) void spmm_kernel(const unsigned short* __restrict__ hb,
                                                   const int2* __restrict__ seg,
                                                   const int* __restrict__ csr_col,
                                                   const float* __restrict__ dinv,
                                                   const float* __restrict__ sq,
                                                   const unsigned short* __restrict__ prev_b,
                                                   const float* __restrict__ wts, int widx,
                                                   unsigned short* __restrict__ yb_out,
                                                   float* __restrict__ axpy_out,
                                                   unsigned short* __restrict__ axpyb_out,
                                                   int n) {
    int plane = blockIdx.x & 1;
    int node = (blockIdx.x >> 1) * 4 + (threadIdx.x >> 6);
    int lane = threadIdx.x & 63;
    if (node >= n) return;
    int sub = lane >> 4, l16 = lane & 15;
    size_t pstride = (size_t)(n + 1) * HALF_CH;
    const unsigned short* hp = hb + (size_t)plane * pstride;

    int2 se = seg[node];
    int s = se.x, e = se.y;
    float acc[8] = {0.f, 0.f, 0.f, 0.f, 0.f, 0.f, 0.f, 0.f};
    if (s < e) {
        int c0 = csr_col[s + 0  + sub];
        int c1 = csr_col[s + 4  + sub];
        int c2 = csr_col[s + 8  + sub];
        int c3 = csr_col[s + 12 + sub];
        int p = s;
        while (true) {
            int pn = p + 16;
            int n0c = csr_col[pn + 0  + sub];   // prefetch next group's cols (slack-safe)
            int n1c = csr_col[pn + 4  + sub];
            int n2c = csr_col[pn + 8  + sub];
            int n3c = csr_col[pn + 12 + sub];
            uint4 v0 = *(const uint4*)(hp + (size_t)c0 * HALF_CH + l16 * 8);
            uint4 v1 = *(const uint4*)(hp + (size_t)c1 * HALF_CH + l16 * 8);
            uint4 v2 = *(const uint4*)(hp + (size_t)c2 * HALF_CH + l16 * 8);
            uint4 v3 = *(const uint4*)(hp + (size_t)c3 * HALF_CH + l16 * 8);
            acc[0] += lo16(v0.x) + lo16(v1.x) + lo16(v2.x) + lo16(v3.x);
            acc[1] += hi16(v0.x) + hi16(v1.x) + hi16(v2.x) + hi16(v3.x);
            acc[2] += lo16(v0.y) + lo16(v1.y) + lo16(v2.y) + lo16(v3.y);
            acc[3] += hi16(v0.y) + hi16(v1.y) + hi16(v2.y) + hi16(v3.y);
            acc[4] += lo16(v0.z) + lo16(v1.z) + lo16(v2.z) + lo16(v3.z);
            acc[5] += hi16(v0.z) + hi16(v1.z) + hi16(v2.z) + hi16(v3.z);
            acc[6] += lo16(v0.w) + lo16(v1.w) + lo16(v2.w) + lo16(v3.w);
            acc[7] += hi16(v0.w) + hi16(v1.w) + hi16(v2.w) + hi16(v3.w);
            c0 = n0c; c1 = n1c; c2 = n2c; c3 = n3c; p = pn;
            if (p >= e) break;
        }
    }
    #pragma unroll
    for (int k = 0; k < 8; k++) {
        acc[k] += __shfl_xor(acc[k], 16, 64);
        acc[k] += __shfl_xor(acc[k], 32, 64);
    }
    if (sub != 0) return;

    float di = dinv[node];
    float y[8];
    #pragma unroll
    for (int k = 0; k < 8; k++) y[k] = di * acc[k];

    size_t pbase = (size_t)plane * pstride + (size_t)node * HALF_CH + l16 * 8;
    size_t padrow = (size_t)plane * pstride + (size_t)n * HALF_CH + l16 * 8;
    if (yb_out) {
        ushort4 o0, o1;
        o0.x = f2b(di * y[0]); o0.y = f2b(di * y[1]); o0.z = f2b(di * y[2]); o0.w = f2b(di * y[3]);
        o1.x = f2b(di * y[4]); o1.y = f2b(di * y[5]); o1.z = f2b(di * y[6]); o1.w = f2b(di * y[7]);
        *(ushort4*)(yb_out + pbase) = o0;
        *(ushort4*)(yb_out + pbase + 4) = o1;
        if (node == 0) {
            ushort4 z = {0, 0, 0, 0};
            *(ushort4*)(yb_out + padrow) = z;
            *(ushort4*)(yb_out + padrow + 4) = z;
        }
    }
    if (prev_b) {
        float wk = wts[widx];
        float sqn = sq[node];
        ushort4 p0 = *(const ushort4*)(prev_b + pbase);
        ushort4 p1 = *(const ushort4*)(prev_b + pbase + 4);
        float o[8];
        o[0] = b2f(p0.x) * sqn + wk * y[0];
        o[1] = b2f(p0.y) * sqn + wk * y[1];
        o[2] = b2f(p0.z) * sqn + wk * y[2];
        o[3] = b2f(p0.w) * sqn + wk * y[3];
        o[4] = b2f(p1.x) * sqn + wk * y[4];
        o[5] = b2f(p1.y) * sqn + wk * y[5];
        o[6] = b2f(p1.z) * sqn + wk * y[6];
        o[7] = b2f(p1.w) * sqn + wk * y[7];
        if (axpy_out) {
            size_t fbase = (size_t)node * OUT_CH + plane * HALF_CH + l16 * 8;
            float4 f0 = {o[0], o[1], o[2], o[3]};
            float4 f1 = {o[4], o[5], o[6], o[7]};
            *(float4*)(axpy_out + fbase) = f0;
            *(float4*)(axpy_out + fbase + 4) = f1;
        }
        if (axpyb_out) {
            ushort4 b0, b1;
            b0.x = f2b(di * o[0]); b0.y = f2b(di * o[1]); b0.z = f2b(di * o[2]); b0.w = f2b(di * o[3]);
            b1.x = f2b(di * o[4]); b1.y = f2b(di * o[5]); b1.z = f2b(di * o[6]); b1.w = f2b(di * o[7]);
            *(ushort4*)(axpyb_out + pbase) = b0;
            *(ushort4*)(axpyb_out + pbase + 4) = b1;
            if (node == 0) {
                ushort4 z = {0, 0, 0, 0};
                *(ushort4*)(axpyb_out + padrow) = z;
                *(ushort4*)(axpyb_out + padrow + 4) = z;
            }
        }
    }
}

extern "C" void kernel_launch(void* const* d_in, const int* in_sizes, int n_in,
                              void* d_out, int out_size, void* d_ws, size_t ws_size,
                              hipStream_t stream) {
    const float* x     = (const float*)d_in[0];
    const int*   ei    = (const int*)d_in[1];   // [2, E]
    const float* lin_w = (const float*)d_in[2]; // [OUT_CH, IN_CH]
    const float* lin_b = (const float*)d_in[3]; // [OUT_CH]
    const float* wts   = (const float*)d_in[4]; // [K]
    float* out = (float*)d_out;

    char* ws = (char*)d_ws;
    size_t off = 0;
    auto alloc = [&](size_t bytes) -> void* {
        void* p = ws + off;
        off += (bytes + 255) & ~(size_t)255;
        return p;
    };
    // cursor32: line-padded; slot +0 = scatter cursor, slot +1 = degree. +1 line for counter.
    int*   cursor32 = (int*)  alloc(((size_t)N_NODES * 32 + 32) * 4);
    int*   counter  = cursor32 + (size_t)N_NODES * 32;
    int2*  seg      = (int2*) alloc((size_t)N_NODES * 8);
    float* dinv     = (float*)alloc(N_NODES * 4);
    float* sq       = (float*)alloc(N_NODES * 4);
    int*   csr_col  = (int*)  alloc((size_t)CSR_CAP * 4);
    unsigned short* h0b   = (unsigned short*)alloc((size_t)2 * (N_NODES + 1) * HALF_CH * 2);
    unsigned short* out1b = (unsigned short*)alloc((size_t)2 * (N_NODES + 1) * HALF_CH * 2);
    unsigned short* t2b   = (unsigned short*)alloc((size_t)2 * (N_NODES + 1) * HALF_CH * 2);

    hipMemsetAsync(cursor32, 0, ((size_t)N_NODES * 32 + 32) * 4, stream);

    const int* row = ei;
    const int* col = ei + E_EDGES;

    deg_kernel<<<(E_EDGES + 255) / 256, 256, 0, stream>>>(row, cursor32, E_EDGES);
    alloc_kernel<<<(N_NODES + 255) / 256, 256, 0, stream>>>(cursor32, seg, dinv, sq,
                                                            counter, csr_col, N_NODES);

    // fused: GEMM (h0b bf16 planar pre-scaled only) || CSR scatter
    gemm_scatter<<<G_GEMM + G_SCAT, 256, 0, stream>>>(x, lin_w, lin_b, dinv, h0b,
                                                      row, col, cursor32, csr_col);

    int sgrid = 2 * ((N_NODES + 3) / 4); // plane = bid&1, 4 nodes/block
    // out1b = dinv*(h0 + w0 * spmm(h0)), h0 reconstructed from h0b
    spmm_kernel<<<sgrid, 256, 0, stream>>>(h0b, seg, csr_col, dinv, sq, h0b,
                                           wts, 0, nullptr, nullptr, out1b, N_NODES);
    // t2b = dinv*spmm(out1)
    spmm_kernel<<<sgrid, 256, 0, stream>>>(out1b, seg, csr_col, dinv, sq, nullptr,
                                           wts, 0, t2b, nullptr, nullptr, N_NODES);
    // out = out1 + w1 * spmm(t2), out1 reconstructed from out1b  (fp32 final)
    spmm_kernel<<<sgrid, 256, 0, stream>>>(t2b, seg, csr_col, dinv, sq, out1b,
                                           wts, 1, nullptr, out, nullptr, N_NODES);
}